// Round 1
// baseline (539.380 us; speedup 1.0000x reference)
//
#include <hip/hip_runtime.h>

typedef unsigned short u16;
typedef __attribute__((ext_vector_type(8))) short bf16x8;   // 8 bf16 = 4 VGPR (guide §3)
typedef __attribute__((ext_vector_type(4))) float f32x4;
typedef __attribute__((ext_vector_type(8))) u16 u16x8;
typedef __attribute__((ext_vector_type(4))) u16 u16x4;
typedef __attribute__((ext_vector_type(4))) float f4;

#define DEVI static __device__ __forceinline__

DEVI u16 f2b(float f) { __bf16 h = (__bf16)f; return __builtin_bit_cast(u16, h); }
DEVI float b2f(u16 h) { unsigned u = ((unsigned)h) << 16; return __builtin_bit_cast(float, u); }

// ---------------------------------------------------------------------------
// Generic tiled MFMA GEMM:
//   C[M,N] = sum_j A_j[M,K_j] @ B_j            (B stored transposed: [N][K_j])
// A either f32 (converted to bf16 while staging to LDS) or bf16.
// 256 threads = 4 waves in a 2x2 grid; wave tile (BM/2)x(BN/2); 16x16x32 MFMA.
// EPI 0: f32 partial to Cout + blockIdx.z*MN (K-split), ldc = N
// EPI 1: bf16 transposed store C^T[N][M], ldc = M
// EPI 3: sigmoid -> f32 row-major, ldc = N
// ---------------------------------------------------------------------------
template<int BM, int BN, bool A_F32, int EPI>
__global__ __launch_bounds__(256)
void gemm_k(const void* A0_, const void* A1_, const u16* B0_, const u16* B1_,
            int K0, int K1, int nA, int KS,
            void* Cout, int ldc, size_t MN)
{
  constexpr int BK = 32;
  constexpr int LD = 40;          // padded LDS row stride in u16 (80 B): 2-way banks = free
  constexpr int MR = BM / 32;
  constexpr int NR = BN / 32;
  __shared__ u16 sA[BM * LD];
  __shared__ u16 sB[BN * LD];

  const int tid  = threadIdx.x;
  const int lane = tid & 63;
  const int wave = tid >> 6;
  const int wm = (wave >> 1) * (BM / 2);
  const int wn = (wave &  1) * (BN / 2);
  const int m0 = blockIdx.y * BM;
  const int n0 = blockIdx.x * BN;
  const int z  = blockIdx.z;

  constexpr int TPRA = 256 / BM;      // threads per A row
  constexpr int EPTA = 32 / TPRA;     // elems per thread (A row chunk)
  constexpr int TPRB = 256 / BN;
  constexpr int EPTB = 32 / TPRB;
  const int ar = tid / TPRA, ac = (tid % TPRA) * EPTA;
  const int br = tid / TPRB, bc = (tid % TPRB) * EPTB;

  f32x4 acc[MR][NR];
#pragma unroll
  for (int m = 0; m < MR; ++m)
#pragma unroll
    for (int n = 0; n < NR; ++n) acc[m][n] = (f32x4){0.f, 0.f, 0.f, 0.f};

  const int lgrp = lane >> 4, lrow = lane & 15;

  for (int j = 0; j < nA; ++j) {
    const void* Aj = j ? A1_ : A0_;
    const u16*  Bj = j ? B1_ : B0_;
    const int Kj = j ? K1 : K0;
    const int Klen = Kj / KS;
    const int kend = (z + 1) * Klen;
    for (int kk = z * Klen; kk < kend; kk += BK) {
      // ---- stage A tile (BM x 32) ----
      if constexpr (A_F32) {
        const float* Ap = (const float*)Aj + (size_t)(m0 + ar) * Kj + kk + ac;
#pragma unroll
        for (int q = 0; q < EPTA / 8; ++q) {
          f4 v0 = ((const f4*)Ap)[2 * q];
          f4 v1 = ((const f4*)Ap)[2 * q + 1];
          u16x8 h;
          h[0]=f2b(v0[0]); h[1]=f2b(v0[1]); h[2]=f2b(v0[2]); h[3]=f2b(v0[3]);
          h[4]=f2b(v1[0]); h[5]=f2b(v1[1]); h[6]=f2b(v1[2]); h[7]=f2b(v1[3]);
          *(u16x8*)&sA[ar * LD + ac + q * 8] = h;
        }
      } else {
        const u16* Ap = (const u16*)Aj + (size_t)(m0 + ar) * Kj + kk + ac;
#pragma unroll
        for (int q = 0; q < EPTA / 8; ++q)
          *(u16x8*)&sA[ar * LD + ac + q * 8] = ((const u16x8*)Ap)[q];
      }
      // ---- stage B tile (BN x 32), already bf16, already [N][K] ----
      {
        const u16* Bp = Bj + (size_t)(n0 + br) * Kj + kk + bc;
#pragma unroll
        for (int q = 0; q < EPTB / 8; ++q)
          *(u16x8*)&sB[br * LD + bc + q * 8] = ((const u16x8*)Bp)[q];
      }
      __syncthreads();
      // ---- fragments + MFMA ----
      bf16x8 af[MR], bfr[NR];
#pragma unroll
      for (int m = 0; m < MR; ++m)
        af[m] = *(const bf16x8*)&sA[(wm + m * 16 + lrow) * LD + lgrp * 8];
#pragma unroll
      for (int n = 0; n < NR; ++n)
        bfr[n] = *(const bf16x8*)&sB[(wn + n * 16 + lrow) * LD + lgrp * 8];
#pragma unroll
      for (int m = 0; m < MR; ++m)
#pragma unroll
        for (int n = 0; n < NR; ++n)
          acc[m][n] = __builtin_amdgcn_mfma_f32_16x16x32_bf16(af[m], bfr[n], acc[m][n], 0, 0, 0);
      __syncthreads();
    }
  }

  // ---- epilogue; C/D layout: col = lane&15, row = (lane>>4)*4 + reg (m89) ----
  if constexpr (EPI == 0) {
    float* Cp = (float*)Cout + (size_t)z * MN;
#pragma unroll
    for (int n = 0; n < NR; ++n) {
      const int c = n0 + wn + n * 16 + lrow;
#pragma unroll
      for (int m = 0; m < MR; ++m) {
        const int rb = m0 + wm + m * 16 + lgrp * 4;
#pragma unroll
        for (int q = 0; q < 4; ++q)
          Cp[(size_t)(rb + q) * ldc + c] = acc[m][n][q];
      }
    }
  } else if constexpr (EPI == 1) {
    u16* Cp = (u16*)Cout;
#pragma unroll
    for (int n = 0; n < NR; ++n) {
      const int c = n0 + wn + n * 16 + lrow;
#pragma unroll
      for (int m = 0; m < MR; ++m) {
        const int rb = m0 + wm + m * 16 + lgrp * 4;
        u16x4 o;
#pragma unroll
        for (int q = 0; q < 4; ++q) o[q] = f2b(acc[m][n][q]);
        *(u16x4*)&Cp[(size_t)c * ldc + rb] = o;   // 8B store, rb%4==0
      }
    }
  } else {  // EPI == 3: sigmoid, f32
    float* Cp = (float*)Cout;
#pragma unroll
    for (int n = 0; n < NR; ++n) {
      const int c = n0 + wn + n * 16 + lrow;
#pragma unroll
      for (int m = 0; m < MR; ++m) {
        const int rb = m0 + wm + m * 16 + lgrp * 4;
#pragma unroll
        for (int q = 0; q < 4; ++q)
          Cp[(size_t)(rb + q) * ldc + c] = 1.f / (1.f + __expf(-acc[m][n][q]));
      }
    }
  }
}

// out[i] = lrelu( sum_z parts[z][i] + mix*b0[c] + (1-mix)*b1[c] )  -> bf16
__global__ __launch_bounds__(256)
void combine_k(const float* parts, int KS, int N, size_t MN,
               const float* b0, const float* b1, const float* mixp, u16* out)
{
  const float mix = *mixp;
  const size_t stride = (size_t)gridDim.x * 1024;
  for (size_t i = ((size_t)blockIdx.x * 256 + threadIdx.x) * 4; i < MN; i += stride) {
    f4 s = {0.f, 0.f, 0.f, 0.f};
    for (int zz = 0; zz < KS; ++zz)
      s += *(const f4*)&parts[(size_t)zz * MN + i];
    const int c = (int)(i % (size_t)N);
    u16x4 o;
#pragma unroll
    for (int q = 0; q < 4; ++q) {
      float v = s[q] + mix * b0[c + q] + (1.f - mix) * b1[c + q];
      v = v >= 0.f ? v : 0.2f * v;
      o[q] = f2b(v);
    }
    *(u16x4*)&out[i] = o;
  }
}

// Wt[n][k] = W[k][n] * s   for all 8 weight matrices (blockIdx.z selects)
__global__ __launch_bounds__(256)
void prep_w(const float* w0, const float* w1, const float* w2, const float* w3,
            const float* w4, const float* w5, const float* w6, const float* w7,
            u16* o0, u16* o1, u16* o2, u16* o3,
            u16* o4, u16* o5, u16* o6, u16* o7,
            const float* ap, const float* bp)
{
  const int zz = blockIdx.z;
  const float a = *ap, b = *bp;
  const float* W; u16* O; int K, N; float s;
  switch (zz) {
    case 0: W=w0; O=o0; K=512; N=256; s=a;       break;
    case 1: W=w1; O=o1; K=256; N=256; s=1.f-a;   break;
    case 2: W=w2; O=o2; K=256; N=256; s=b;       break;
    case 3: W=w3; O=o3; K=512; N=256; s=1.f-b;   break;
    case 4: W=w4; O=o4; K=256; N=64;  s=a;       break;
    case 5: W=w5; O=o5; K=256; N=64;  s=1.f-a;   break;
    case 6: W=w6; O=o6; K=256; N=64;  s=b;       break;
    default:W=w7; O=o7; K=256; N=64;  s=1.f-b;   break;
  }
  const int total = K * N;
  for (int i = blockIdx.x * 256 + threadIdx.x; i < total; i += gridDim.x * 256) {
    const int k = i / N, n = i - k * N;
    O[n * K + k] = f2b(W[i] * s);
  }
}

// one wave per row: out[r][c] = x[r][c] - max - log(sum exp(x - max))
__global__ __launch_bounds__(256)
void softmax_k(const u16* x, float* out)
{
  const int row  = blockIdx.x * 4 + (threadIdx.x >> 6);
  const int lane = threadIdx.x & 63;
  const float v = b2f(x[row * 64 + lane]);
  float m = v;
#pragma unroll
  for (int off = 32; off; off >>= 1) m = fmaxf(m, __shfl_xor(m, off));
  float s = __expf(v - m);
#pragma unroll
  for (int off = 32; off; off >>= 1) s += __shfl_xor(s, off);
  out[(size_t)row * 64 + lane] = v - m - __logf(s);
}

extern "C" void kernel_launch(void* const* d_in, const int* in_sizes, int n_in,
                              void* d_out, int out_size, void* d_ws, size_t ws_size,
                              hipStream_t stream)
{
  const float* hx1 = (const float*)d_in[0];
  const float* hx2 = (const float*)d_in[1];
  const float* x0  = (const float*)d_in[2];
  const float* hy1 = (const float*)d_in[3];
  const float* hy2 = (const float*)d_in[4];
  const float* y0  = (const float*)d_in[5];
  const float* alphap = (const float*)d_in[6];
  const float* betap  = (const float*)d_in[7];
  const float* Wx1a = (const float*)d_in[8];  const float* bx1a = (const float*)d_in[9];
  const float* Wx1b = (const float*)d_in[10]; const float* bx1b = (const float*)d_in[11];
  const float* Wx2a = (const float*)d_in[12]; const float* bx2a = (const float*)d_in[13];
  const float* Wx2b = (const float*)d_in[14]; const float* bx2b = (const float*)d_in[15];
  const float* Wy1a = (const float*)d_in[16]; const float* by1a = (const float*)d_in[17];
  const float* Wy1b = (const float*)d_in[18]; const float* by1b = (const float*)d_in[19];
  const float* Wy2a = (const float*)d_in[20]; const float* by2a = (const float*)d_in[21];
  const float* Wy2b = (const float*)d_in[22]; const float* by2b = (const float*)d_in[23];
  (void)in_sizes; (void)n_in; (void)out_size; (void)ws_size;

  constexpr int Nx = 8192, Ny = 4096, Fx = 512, Fy = 256, D1 = 256, C = 64;

  // ---- workspace layout (u16 elems, 16B aligned), total ~25 MB ----
  u16* ws = (u16*)d_ws;
  size_t off = 0;
  auto alloc = [&](size_t n) { u16* p = ws + off; off += (n + 15) & ~(size_t)15; return p; };
  u16* WtX1a = alloc((size_t)D1 * Fx);
  u16* WtX1b = alloc((size_t)D1 * Fy);
  u16* WtY1a = alloc((size_t)D1 * Fy);
  u16* WtY1b = alloc((size_t)D1 * Fx);
  u16* WtX2a = alloc((size_t)C * D1);
  u16* WtX2b = alloc((size_t)C * D1);
  u16* WtY2a = alloc((size_t)C * D1);
  u16* WtY2b = alloc((size_t)C * D1);
  u16* B1x  = alloc((size_t)D1 * Nx);   // (x0@Wx1a*a)^T      [256][8192]
  u16* B2x  = alloc((size_t)D1 * Ny);   // (y0@Wx1b*(1-a))^T  [256][4096]
  u16* B1y  = alloc((size_t)D1 * Ny);
  u16* B2y  = alloc((size_t)D1 * Nx);
  u16* x1   = alloc((size_t)Nx * D1);   // bf16 row-major
  u16* y1   = alloc((size_t)Ny * D1);
  u16* B1x2 = alloc((size_t)C * Nx);
  u16* B2x2 = alloc((size_t)C * Ny);
  u16* B1y2 = alloc((size_t)C * Ny);
  u16* B2y2 = alloc((size_t)C * Nx);
  u16* x2   = alloc((size_t)Nx * C);
  u16* y2   = alloc((size_t)Ny * C);
  // K-split f32 partials live in d_out (<=32MB, overwritten by h_hat at the end)
  float* part = (float*)d_out;

  // 1) weights -> transposed, scaled bf16
  prep_w<<<dim3(512, 1, 8), 256, 0, stream>>>(Wx1a, Wx1b, Wy1a, Wy1b, Wx2a, Wx2b, Wy2a, Wy2b,
      WtX1a, WtX1b, WtY1a, WtY1b, WtX2a, WtX2b, WtY2a, WtY2b, alphap, betap);

  // 2) layer-1 small GEMMs (transposed bf16 outputs)
  gemm_k<64,64,true,1><<<dim3(D1/64, Nx/64), 256, 0, stream>>>(x0, nullptr, WtX1a, nullptr, Fx, 0, 1, 1, B1x, Nx, 0);
  gemm_k<64,64,true,1><<<dim3(D1/64, Ny/64), 256, 0, stream>>>(y0, nullptr, WtX1b, nullptr, Fy, 0, 1, 1, B2x, Ny, 0);
  gemm_k<64,64,true,1><<<dim3(D1/64, Ny/64), 256, 0, stream>>>(y0, nullptr, WtY1a, nullptr, Fy, 0, 1, 1, B1y, Ny, 0);
  gemm_k<64,64,true,1><<<dim3(D1/64, Nx/64), 256, 0, stream>>>(x0, nullptr, WtY1b, nullptr, Fx, 0, 1, 1, B2y, Nx, 0);

  // 3) layer-1 big adjacency GEMMs (K-split partials) + combine (bias + lrelu -> bf16)
  const size_t MNx1 = (size_t)Nx * D1, MNy1 = (size_t)Ny * D1;
  gemm_k<128,128,true,0><<<dim3(D1/128, Nx/128, 4), 256, 0, stream>>>(hx1, hx2, B1x, B2x, Nx, Ny, 2, 4, part, D1, MNx1);
  combine_k<<<dim3(2048), 256, 0, stream>>>(part, 4, D1, MNx1, bx1a, bx1b, alphap, x1);
  gemm_k<128,128,true,0><<<dim3(D1/128, Ny/128, 8), 256, 0, stream>>>(hy1, hy2, B1y, B2y, Ny, Nx, 2, 8, part, D1, MNy1);
  combine_k<<<dim3(1024), 256, 0, stream>>>(part, 8, D1, MNy1, by1a, by1b, betap, y1);

  // 4) layer-2 small GEMMs (bf16 A)
  gemm_k<64,64,false,1><<<dim3(C/64, Nx/64), 256, 0, stream>>>(x1, nullptr, WtX2a, nullptr, D1, 0, 1, 1, B1x2, Nx, 0);
  gemm_k<64,64,false,1><<<dim3(C/64, Ny/64), 256, 0, stream>>>(y1, nullptr, WtX2b, nullptr, D1, 0, 1, 1, B2x2, Ny, 0);
  gemm_k<64,64,false,1><<<dim3(C/64, Ny/64), 256, 0, stream>>>(y1, nullptr, WtY2a, nullptr, D1, 0, 1, 1, B1y2, Ny, 0);
  gemm_k<64,64,false,1><<<dim3(C/64, Nx/64), 256, 0, stream>>>(x1, nullptr, WtY2b, nullptr, D1, 0, 1, 1, B2y2, Nx, 0);

  // 5) layer-2 big adjacency GEMMs
  const size_t MNx2 = (size_t)Nx * C, MNy2 = (size_t)Ny * C;
  gemm_k<128,64,true,0><<<dim3(C/64, Nx/128, 8), 256, 0, stream>>>(hx1, hx2, B1x2, B2x2, Nx, Ny, 2, 8, part, C, MNx2);
  combine_k<<<dim3(512), 256, 0, stream>>>(part, 8, C, MNx2, bx2a, bx2b, alphap, x2);
  gemm_k<128,64,true,0><<<dim3(C/64, Ny/128, 16), 256, 0, stream>>>(hy1, hy2, B1y2, B2y2, Ny, Nx, 2, 16, part, C, MNy2);
  combine_k<<<dim3(256), 256, 0, stream>>>(part, 16, C, MNy2, by2a, by2b, betap, y2);

  // 6) h_hat = sigmoid(x2 @ y2^T) -> d_out[0 : Nx*Ny]  (y2 row-major == B^T layout)
  gemm_k<128,128,false,3><<<dim3(Ny/128, Nx/128, 1), 256, 0, stream>>>(x2, nullptr, y2, nullptr, C, 0, 1, 1, d_out, Ny, 0);

  // 7) x_output = log_softmax(x2) -> d_out[Nx*Ny : ]
  softmax_k<<<dim3(Nx/4), 256, 0, stream>>>(x2, (float*)d_out + (size_t)Nx * Ny);
}

// Round 2
// 413.043 us; speedup vs baseline: 1.3059x; 1.3059x over previous
//
#include <hip/hip_runtime.h>

typedef unsigned short u16;
typedef unsigned char u8;
typedef long i64;
typedef __attribute__((ext_vector_type(8))) short bf16x8;
typedef __attribute__((ext_vector_type(4))) float f32x4;
typedef __attribute__((ext_vector_type(8))) u16 u16x8;
typedef __attribute__((ext_vector_type(4))) u16 u16x4;
typedef __attribute__((ext_vector_type(4))) float f4;
typedef __attribute__((ext_vector_type(4))) int i32x4;

#define DEVI static __device__ __forceinline__

DEVI u16 f2b(float f) { __bf16 h = (__bf16)f; return __builtin_bit_cast(u16, h); }
DEVI float b2f(u16 h) { unsigned u = ((unsigned)h) << 16; return __builtin_bit_cast(float, u); }

DEVI int pk8(float a, float b, float c, float d) {
  int w = __builtin_amdgcn_cvt_pk_fp8_f32(a, b, 0, false);
  return __builtin_amdgcn_cvt_pk_fp8_f32(c, d, w, true);
}

DEVI void gload16(const void* g, void* l) {
  __builtin_amdgcn_global_load_lds((const __attribute__((address_space(1))) void*)g,
                                   (__attribute__((address_space(3))) void*)l, 16, 0, 0);
}

// ---------------------------------------------------------------------------
// f32 -> fp8 e4m3 (scaled) streaming conversion, 16 elems/thread/iter
// ---------------------------------------------------------------------------
__global__ __launch_bounds__(256)
void cvtA_k(const float* __restrict__ in, u8* __restrict__ out, size_t n16, float s)
{
  size_t i = (size_t)blockIdx.x * 256 + threadIdx.x;
  const size_t stride = (size_t)gridDim.x * 256;
  for (; i < n16; i += stride) {
    const f4* p = (const f4*)(in + i * 16);
    f4 v0 = p[0], v1 = p[1], v2 = p[2], v3 = p[3];
    i32x4 o;
    o.x = pk8(v0[0]*s, v0[1]*s, v0[2]*s, v0[3]*s);
    o.y = pk8(v1[0]*s, v1[1]*s, v1[2]*s, v1[3]*s);
    o.z = pk8(v2[0]*s, v2[1]*s, v2[2]*s, v2[3]*s);
    o.w = pk8(v3[0]*s, v3[1]*s, v3[2]*s, v3[3]*s);
    *(i32x4*)(out + i * 16) = o;
  }
}

// ---------------------------------------------------------------------------
// fp8 big GEMM, 2-phase pipelined via global_load_lds (T3-minimum recipe).
//   C[M,N] += A0[M,K0]@B0^T + A1[M,K1]@B1^T   (B stored [N][K] fp8)
// BM=128, BK=128 bytes, 4 waves 2x2. XOR-swizzle (row&7)<<4 on BOTH sides
// (pre-swizzled global source + swizzled ds_read) -> 2-way banks = free.
// K-split over blockIdx.z writes f32 partials at Cout + z*MN.
// Grids must be a multiple of 8 blocks (XCD swizzle assumes it).
// ---------------------------------------------------------------------------
template<int BN>
__global__ __launch_bounds__(256)
void gemm8_k(const u8* __restrict__ A0, const u8* __restrict__ A1,
             const u8* __restrict__ B0, const u8* __restrict__ B1,
             int K0, int K1, int L0, int L1,
             float* __restrict__ Cout, int N, size_t MN)
{
  constexpr int BM = 128, BK = 128;
  constexpr int MR = 4, NR = BN / 32;
  constexpr int ASZ = BM * BK, BSZ = BN * BK;
  __shared__ u8 lds[2 * (ASZ + BSZ)];

  const int tid = threadIdx.x, lane = tid & 63, wave = tid >> 6;
  const int wm = (wave >> 1) * 64, wn = (wave & 1) * (BN / 2);
  const int lgrp = lane >> 4, lrow = lane & 15;

  // XCD-chunked bijective block swizzle (nwg % 8 == 0 for all our grids)
  const int gx = gridDim.x, gy = gridDim.y;
  const int flat = blockIdx.x + gx * (blockIdx.y + gy * blockIdx.z);
  const int nwg = gx * gy * gridDim.z;
  const int swz = (flat & 7) * (nwg >> 3) + (flat >> 3);
  const int n0 = (swz % gx) * BN;
  const int m0 = ((swz / gx) % gy) * BM;
  const int z  = swz / (gx * gy);

  const int nt0 = L0 >> 7, nt1 = L1 >> 7, NT = nt0 + nt1;

  f32x4 acc[MR][NR];
#pragma unroll
  for (int m = 0; m < MR; ++m)
#pragma unroll
    for (int n = 0; n < NR; ++n) acc[m][n] = (f32x4){0.f, 0.f, 0.f, 0.f};

  auto stage = [&](int buf, int t) {
    const u8* Ap; const u8* Bp; int Kj, kk;
    if (t < nt0) { Ap = A0; Bp = B0; Kj = K0; kk = z * L0 + (t << 7); }
    else         { Ap = A1; Bp = B1; Kj = K1; kk = z * L1 + ((t - nt0) << 7); }
    u8* sA = &lds[buf * (ASZ + BSZ)];
    u8* sB = sA + ASZ;
#pragma unroll
    for (int i = 0; i < ASZ / 4096; ++i) {
      const int off = i * 4096 + tid * 16;
      const int r = off >> 7, c = off & 127;
      gload16(Ap + (size_t)(m0 + r) * Kj + kk + (c ^ ((r & 7) << 4)), sA + off);
    }
#pragma unroll
    for (int i = 0; i < BSZ / 4096; ++i) {
      const int off = i * 4096 + tid * 16;
      const int r = off >> 7, c = off & 127;
      gload16(Bp + (size_t)(n0 + r) * Kj + kk + (c ^ ((r & 7) << 4)), sB + off);
    }
  };

  auto compute = [&](int buf) {
    const u8* sA = &lds[buf * (ASZ + BSZ)];
    const u8* sB = sA + ASZ;
#pragma unroll
    for (int ks = 0; ks < 4; ++ks) {
      i64 a[MR], b[NR];
#pragma unroll
      for (int m = 0; m < MR; ++m) {
        const int r = wm + m * 16 + lrow;
        a[m] = *(const i64*)&sA[r * BK + ((ks * 32 + lgrp * 8) ^ ((r & 7) << 4))];
      }
#pragma unroll
      for (int n = 0; n < NR; ++n) {
        const int r = wn + n * 16 + lrow;
        b[n] = *(const i64*)&sB[r * BK + ((ks * 32 + lgrp * 8) ^ ((r & 7) << 4))];
      }
#pragma unroll
      for (int m = 0; m < MR; ++m)
#pragma unroll
        for (int n = 0; n < NR; ++n)
          acc[m][n] = __builtin_amdgcn_mfma_f32_16x16x32_fp8_fp8(a[m], b[n], acc[m][n], 0, 0, 0);
    }
  };

  stage(0, 0);
  asm volatile("s_waitcnt vmcnt(0)" ::: "memory");
  __syncthreads();
  for (int t = 0; t < NT; ++t) {
    const int cur = t & 1;
    if (t + 1 < NT) stage(cur ^ 1, t + 1);
    compute(cur);
    asm volatile("s_waitcnt vmcnt(0)" ::: "memory");
    __syncthreads();
  }

  float* Cp = Cout + (size_t)z * MN;
#pragma unroll
  for (int n = 0; n < NR; ++n) {
    const int c = n0 + wn + n * 16 + lrow;
#pragma unroll
    for (int m = 0; m < MR; ++m) {
      const int rb = m0 + wm + m * 16 + lgrp * 4;
#pragma unroll
      for (int q = 0; q < 4; ++q)
        Cp[(size_t)(rb + q) * N + c] = acc[m][n][q];
    }
  }
}

// ---------------------------------------------------------------------------
// Generic tiled bf16 MFMA GEMM (small GEMMs + h_hat + path-C bigs).
// EPI 0: f32 partial (K-split); EPI 1: bf16 C^T; EPI 2: fp8 C^T * sOut;
// EPI 3: sigmoid f32 row-major.
// ---------------------------------------------------------------------------
template<int BM, int BN, bool A_F32, int EPI>
__global__ __launch_bounds__(256)
void gemm_k(const void* A0_, const void* A1_, const u16* B0_, const u16* B1_,
            int K0, int K1, int nA, int KS,
            void* Cout, int ldc, size_t MN, float sOut)
{
  constexpr int BK = 32;
  constexpr int LD = 40;
  constexpr int MR = BM / 32;
  constexpr int NR = BN / 32;
  __shared__ u16 sA[BM * LD];
  __shared__ u16 sB[BN * LD];

  const int tid  = threadIdx.x;
  const int lane = tid & 63;
  const int wave = tid >> 6;
  const int wm = (wave >> 1) * (BM / 2);
  const int wn = (wave &  1) * (BN / 2);
  const int m0 = blockIdx.y * BM;
  const int n0 = blockIdx.x * BN;
  const int z  = blockIdx.z;

  constexpr int TPRA = 256 / BM;
  constexpr int EPTA = 32 / TPRA;
  constexpr int TPRB = 256 / BN;
  constexpr int EPTB = 32 / TPRB;
  const int ar = tid / TPRA, ac = (tid % TPRA) * EPTA;
  const int br = tid / TPRB, bc = (tid % TPRB) * EPTB;

  f32x4 acc[MR][NR];
#pragma unroll
  for (int m = 0; m < MR; ++m)
#pragma unroll
    for (int n = 0; n < NR; ++n) acc[m][n] = (f32x4){0.f, 0.f, 0.f, 0.f};

  const int lgrp = lane >> 4, lrow = lane & 15;

  for (int j = 0; j < nA; ++j) {
    const void* Aj = j ? A1_ : A0_;
    const u16*  Bj = j ? B1_ : B0_;
    const int Kj = j ? K1 : K0;
    const int Klen = Kj / KS;
    const int kend = (z + 1) * Klen;
    for (int kk = z * Klen; kk < kend; kk += BK) {
      if constexpr (A_F32) {
        const float* Ap = (const float*)Aj + (size_t)(m0 + ar) * Kj + kk + ac;
#pragma unroll
        for (int q = 0; q < EPTA / 8; ++q) {
          f4 v0 = ((const f4*)Ap)[2 * q];
          f4 v1 = ((const f4*)Ap)[2 * q + 1];
          u16x8 h;
          h[0]=f2b(v0[0]); h[1]=f2b(v0[1]); h[2]=f2b(v0[2]); h[3]=f2b(v0[3]);
          h[4]=f2b(v1[0]); h[5]=f2b(v1[1]); h[6]=f2b(v1[2]); h[7]=f2b(v1[3]);
          *(u16x8*)&sA[ar * LD + ac + q * 8] = h;
        }
      } else {
        const u16* Ap = (const u16*)Aj + (size_t)(m0 + ar) * Kj + kk + ac;
#pragma unroll
        for (int q = 0; q < EPTA / 8; ++q)
          *(u16x8*)&sA[ar * LD + ac + q * 8] = ((const u16x8*)Ap)[q];
      }
      {
        const u16* Bp = Bj + (size_t)(n0 + br) * Kj + kk + bc;
#pragma unroll
        for (int q = 0; q < EPTB / 8; ++q)
          *(u16x8*)&sB[br * LD + bc + q * 8] = ((const u16x8*)Bp)[q];
      }
      __syncthreads();
      bf16x8 af[MR], bfr[NR];
#pragma unroll
      for (int m = 0; m < MR; ++m)
        af[m] = *(const bf16x8*)&sA[(wm + m * 16 + lrow) * LD + lgrp * 8];
#pragma unroll
      for (int n = 0; n < NR; ++n)
        bfr[n] = *(const bf16x8*)&sB[(wn + n * 16 + lrow) * LD + lgrp * 8];
#pragma unroll
      for (int m = 0; m < MR; ++m)
#pragma unroll
        for (int n = 0; n < NR; ++n)
          acc[m][n] = __builtin_amdgcn_mfma_f32_16x16x32_bf16(af[m], bfr[n], acc[m][n], 0, 0, 0);
      __syncthreads();
    }
  }

  if constexpr (EPI == 0) {
    float* Cp = (float*)Cout + (size_t)z * MN;
#pragma unroll
    for (int n = 0; n < NR; ++n) {
      const int c = n0 + wn + n * 16 + lrow;
#pragma unroll
      for (int m = 0; m < MR; ++m) {
        const int rb = m0 + wm + m * 16 + lgrp * 4;
#pragma unroll
        for (int q = 0; q < 4; ++q)
          Cp[(size_t)(rb + q) * ldc + c] = acc[m][n][q];
      }
    }
  } else if constexpr (EPI == 1) {
    u16* Cp = (u16*)Cout;
#pragma unroll
    for (int n = 0; n < NR; ++n) {
      const int c = n0 + wn + n * 16 + lrow;
#pragma unroll
      for (int m = 0; m < MR; ++m) {
        const int rb = m0 + wm + m * 16 + lgrp * 4;
        u16x4 o;
#pragma unroll
        for (int q = 0; q < 4; ++q) o[q] = f2b(acc[m][n][q]);
        *(u16x4*)&Cp[(size_t)c * ldc + rb] = o;
      }
    }
  } else if constexpr (EPI == 2) {
    u8* Cp = (u8*)Cout;
#pragma unroll
    for (int n = 0; n < NR; ++n) {
      const int c = n0 + wn + n * 16 + lrow;
#pragma unroll
      for (int m = 0; m < MR; ++m) {
        const int rb = m0 + wm + m * 16 + lgrp * 4;
        int w = __builtin_amdgcn_cvt_pk_fp8_f32(acc[m][n][0] * sOut, acc[m][n][1] * sOut, 0, false);
        w = __builtin_amdgcn_cvt_pk_fp8_f32(acc[m][n][2] * sOut, acc[m][n][3] * sOut, w, true);
        *(int*)&Cp[(size_t)c * ldc + rb] = w;
      }
    }
  } else {
    float* Cp = (float*)Cout;
#pragma unroll
    for (int n = 0; n < NR; ++n) {
      const int c = n0 + wn + n * 16 + lrow;
#pragma unroll
      for (int m = 0; m < MR; ++m) {
        const int rb = m0 + wm + m * 16 + lgrp * 4;
#pragma unroll
        for (int q = 0; q < 4; ++q)
          Cp[(size_t)(rb + q) * ldc + c] = 1.f / (1.f + __expf(-acc[m][n][q]));
      }
    }
  }
}

// out[i] = lrelu( invs*sum_z parts[z][i] + mix*b0[c] + (1-mix)*b1[c] ) -> bf16
__global__ __launch_bounds__(256)
void combine_k(const float* __restrict__ parts, int KS, int N, size_t MN,
               const float* b0, const float* b1, const float* mixp, u16* out, float invs)
{
  const float mix = *mixp;
  const size_t stride = (size_t)gridDim.x * 1024;
  for (size_t i = ((size_t)blockIdx.x * 256 + threadIdx.x) * 4; i < MN; i += stride) {
    f4 s = {0.f, 0.f, 0.f, 0.f};
    for (int zz = 0; zz < KS; ++zz)
      s += *(const f4*)&parts[(size_t)zz * MN + i];
    const int c = (int)(i % (size_t)N);
    u16x4 o;
#pragma unroll
    for (int q = 0; q < 4; ++q) {
      float v = s[q] * invs + mix * b0[c + q] + (1.f - mix) * b1[c + q];
      v = v >= 0.f ? v : 0.2f * v;
      o[q] = f2b(v);
    }
    *(u16x4*)&out[i] = o;
  }
}

// Wt[n][k] = W[k][n] * s  (bf16) for the 8 weight matrices
__global__ __launch_bounds__(256)
void prep_w(const float* w0, const float* w1, const float* w2, const float* w3,
            const float* w4, const float* w5, const float* w6, const float* w7,
            u16* o0, u16* o1, u16* o2, u16* o3,
            u16* o4, u16* o5, u16* o6, u16* o7,
            const float* ap, const float* bp)
{
  const int zz = blockIdx.z;
  const float a = *ap, b = *bp;
  const float* W; u16* O; int K, N; float s;
  switch (zz) {
    case 0: W=w0; O=o0; K=512; N=256; s=a;       break;
    case 1: W=w1; O=o1; K=256; N=256; s=1.f-a;   break;
    case 2: W=w2; O=o2; K=256; N=256; s=b;       break;
    case 3: W=w3; O=o3; K=512; N=256; s=1.f-b;   break;
    case 4: W=w4; O=o4; K=256; N=64;  s=a;       break;
    case 5: W=w5; O=o5; K=256; N=64;  s=1.f-a;   break;
    case 6: W=w6; O=o6; K=256; N=64;  s=b;       break;
    default:W=w7; O=o7; K=256; N=64;  s=1.f-b;   break;
  }
  const int total = K * N;
  for (int i = blockIdx.x * 256 + threadIdx.x; i < total; i += gridDim.x * 256) {
    const int k = i / N, n = i - k * N;
    O[n * K + k] = f2b(W[i] * s);
  }
}

__global__ __launch_bounds__(256)
void softmax_k(const u16* x, float* out)
{
  const int row  = blockIdx.x * 4 + (threadIdx.x >> 6);
  const int lane = threadIdx.x & 63;
  const float v = b2f(x[row * 64 + lane]);
  float m = v;
#pragma unroll
  for (int off = 32; off; off >>= 1) m = fmaxf(m, __shfl_xor(m, off));
  float s = __expf(v - m);
#pragma unroll
  for (int off = 32; off; off >>= 1) s += __shfl_xor(s, off);
  out[(size_t)row * 64 + lane] = v - m - __logf(s);
}

extern "C" void kernel_launch(void* const* d_in, const int* in_sizes, int n_in,
                              void* d_out, int out_size, void* d_ws, size_t ws_size,
                              hipStream_t stream)
{
  const float* hx1 = (const float*)d_in[0];
  const float* hx2 = (const float*)d_in[1];
  const float* x0  = (const float*)d_in[2];
  const float* hy1 = (const float*)d_in[3];
  const float* hy2 = (const float*)d_in[4];
  const float* y0  = (const float*)d_in[5];
  const float* alphap = (const float*)d_in[6];
  const float* betap  = (const float*)d_in[7];
  const float* Wx1a = (const float*)d_in[8];  const float* bx1a = (const float*)d_in[9];
  const float* Wx1b = (const float*)d_in[10]; const float* bx1b = (const float*)d_in[11];
  const float* Wx2a = (const float*)d_in[12]; const float* bx2a = (const float*)d_in[13];
  const float* Wx2b = (const float*)d_in[14]; const float* bx2b = (const float*)d_in[15];
  const float* Wy1a = (const float*)d_in[16]; const float* by1a = (const float*)d_in[17];
  const float* Wy1b = (const float*)d_in[18]; const float* by1b = (const float*)d_in[19];
  const float* Wy2a = (const float*)d_in[20]; const float* by2a = (const float*)d_in[21];
  const float* Wy2b = (const float*)d_in[22]; const float* by2b = (const float*)d_in[23];
  (void)in_sizes; (void)n_in; (void)out_size;

  constexpr int Nx = 8192, Ny = 4096, Fx = 512, Fy = 256, D1 = 256, C = 64;
  constexpr float SADJ = 8192.f;           // adjacency fp8 pre-scale (2^13)
  constexpr float SB1 = 16.f, SB2 = 256.f; // big-GEMM B fp8 pre-scales
  constexpr float INV1 = 1.f / (8192.f * 16.f);
  constexpr float INV2 = 1.f / (8192.f * 256.f);

  // ---- byte allocator on ws ----
  u8* wsb = (u8*)d_ws;
  size_t off = 0;
  auto alloc = [&](size_t n) { u8* p = wsb + off; off += (n + 63) & ~(size_t)63; return p; };

  u16* WtX1a = (u16*)alloc((size_t)D1 * Fx * 2);
  u16* WtX1b = (u16*)alloc((size_t)D1 * Fy * 2);
  u16* WtY1a = (u16*)alloc((size_t)D1 * Fy * 2);
  u16* WtY1b = (u16*)alloc((size_t)D1 * Fx * 2);
  u16* WtX2a = (u16*)alloc((size_t)C * D1 * 2);
  u16* WtX2b = (u16*)alloc((size_t)C * D1 * 2);
  u16* WtY2a = (u16*)alloc((size_t)C * D1 * 2);
  u16* WtY2b = (u16*)alloc((size_t)C * D1 * 2);
  // big-GEMM B operands: path A/B -> fp8 (1B), path C -> bf16 (2B). Alloc 2B.
  u8* B1x  = alloc((size_t)D1 * Nx * 2);
  u8* B2x  = alloc((size_t)D1 * Ny * 2);
  u8* B1y  = alloc((size_t)D1 * Ny * 2);
  u8* B2y  = alloc((size_t)D1 * Nx * 2);
  u16* x1  = (u16*)alloc((size_t)Nx * D1 * 2);
  u16* y1  = (u16*)alloc((size_t)Ny * D1 * 2);
  u8* B1x2 = alloc((size_t)C * Nx * 2);
  u8* B2x2 = alloc((size_t)C * Ny * 2);
  u8* B1y2 = alloc((size_t)C * Ny * 2);
  u8* B2y2 = alloc((size_t)C * Nx * 2);
  u16* x2  = (u16*)alloc((size_t)Nx * C * 2);
  u16* y2  = (u16*)alloc((size_t)Ny * C * 2);

  const size_t base_off = off;
  const size_t szHx1 = (size_t)Nx * Nx, szHx2 = (size_t)Nx * Ny;
  const size_t szHy1 = (size_t)Ny * Ny, szHy2 = (size_t)Ny * Nx;
  const size_t needA = base_off + szHx1 + szHx2 + szHy1 + szHy2 + ((size_t)32 << 20) + (1 << 20);
  const size_t needB = base_off + szHy1 + szHy2 + (1 << 20);

  const size_t MNx1 = (size_t)Nx * D1, MNy1 = (size_t)Ny * D1;
  const size_t MNx2 = (size_t)Nx * C,  MNy2 = (size_t)Ny * C;

  prep_w<<<dim3(512, 1, 8), 256, 0, stream>>>(Wx1a, Wx1b, Wy1a, Wy1b, Wx2a, Wx2b, Wy2a, Wy2b,
      WtX1a, WtX1b, WtY1a, WtY1b, WtX2a, WtX2b, WtY2a, WtY2b, alphap, betap);

  if (ws_size >= needB) {
    // ================== fp8 fast path (A: all-ws, B: hx+partials in d_out) =========
    u8 *hx1f8, *hx2f8, *hy1f8, *hy2f8; float* part;
    if (ws_size >= needA) {
      hx1f8 = alloc(szHx1); hx2f8 = alloc(szHx2);
      hy1f8 = alloc(szHy1); hy2f8 = alloc(szHy2);
      part  = (float*)alloc((size_t)32 << 20);
    } else {
      hy1f8 = alloc(szHy1); hy2f8 = alloc(szHy2);
      hx1f8 = (u8*)d_out;                 // 64 MiB
      hx2f8 = (u8*)d_out + szHx1;         // 32 MiB; ends at 96 MiB
      part  = (float*)((u8*)d_out + szHx1 + szHx2);   // 32 MiB; ends at 128 MiB (< h_hat size)
    }

    // adjacency f32 -> fp8 (scaled 2^13)
    cvtA_k<<<2048, 256, 0, stream>>>(hx1, hx1f8, szHx1 / 16, SADJ);
    cvtA_k<<<2048, 256, 0, stream>>>(hx2, hx2f8, szHx2 / 16, SADJ);
    cvtA_k<<<1024, 256, 0, stream>>>(hy1, hy1f8, szHy1 / 16, SADJ);
    cvtA_k<<<2048, 256, 0, stream>>>(hy2, hy2f8, szHy2 / 16, SADJ);

    // layer-1 small GEMMs -> fp8 transposed B (scaled x16)
    gemm_k<64,64,true,2><<<dim3(D1/64, Nx/64), 256, 0, stream>>>(x0, nullptr, WtX1a, nullptr, Fx, 0, 1, 1, B1x, Nx, 0, SB1);
    gemm_k<64,64,true,2><<<dim3(D1/64, Ny/64), 256, 0, stream>>>(y0, nullptr, WtX1b, nullptr, Fy, 0, 1, 1, B2x, Ny, 0, SB1);
    gemm_k<64,64,true,2><<<dim3(D1/64, Ny/64), 256, 0, stream>>>(y0, nullptr, WtY1a, nullptr, Fy, 0, 1, 1, B1y, Ny, 0, SB1);
    gemm_k<64,64,true,2><<<dim3(D1/64, Nx/64), 256, 0, stream>>>(x0, nullptr, WtY1b, nullptr, Fx, 0, 1, 1, B2y, Nx, 0, SB1);

    // layer-1 big GEMMs (fp8, pipelined) + combine
    gemm8_k<128><<<dim3(2, 64, 4), 256, 0, stream>>>(hx1f8, hx2f8, B1x, B2x, Nx, Ny, 2048, 1024, part, D1, MNx1);
    combine_k<<<dim3(2048), 256, 0, stream>>>(part, 4, D1, MNx1, bx1a, bx1b, alphap, x1, INV1);
    gemm8_k<128><<<dim3(2, 32, 8), 256, 0, stream>>>(hy1f8, hy2f8, B1y, B2y, Ny, Nx, 512, 1024, part, D1, MNy1);
    combine_k<<<dim3(1024), 256, 0, stream>>>(part, 8, D1, MNy1, by1a, by1b, betap, y1, INV1);

    // layer-2 small GEMMs (bf16 A) -> fp8 B (scaled x256)
    gemm_k<64,64,false,2><<<dim3(C/64, Nx/64), 256, 0, stream>>>(x1, nullptr, WtX2a, nullptr, D1, 0, 1, 1, B1x2, Nx, 0, SB2);
    gemm_k<64,64,false,2><<<dim3(C/64, Ny/64), 256, 0, stream>>>(y1, nullptr, WtX2b, nullptr, D1, 0, 1, 1, B2x2, Ny, 0, SB2);
    gemm_k<64,64,false,2><<<dim3(C/64, Ny/64), 256, 0, stream>>>(y1, nullptr, WtY2a, nullptr, D1, 0, 1, 1, B1y2, Ny, 0, SB2);
    gemm_k<64,64,false,2><<<dim3(C/64, Nx/64), 256, 0, stream>>>(x1, nullptr, WtY2b, nullptr, D1, 0, 1, 1, B2y2, Nx, 0, SB2);

    // layer-2 big GEMMs
    gemm8_k<64><<<dim3(1, 64, 8), 256, 0, stream>>>(hx1f8, hx2f8, B1x2, B2x2, Nx, Ny, 1024, 512, part, C, MNx2);
    combine_k<<<dim3(512), 256, 0, stream>>>(part, 8, C, MNx2, bx2a, bx2b, alphap, x2, INV2);
    gemm8_k<64><<<dim3(1, 32, 16), 256, 0, stream>>>(hy1f8, hy2f8, B1y2, B2y2, Ny, Nx, 256, 512, part, C, MNy2);
    combine_k<<<dim3(256), 256, 0, stream>>>(part, 16, C, MNy2, by2a, by2b, betap, y2, INV2);
  } else {
    // ================== path C: round-1 fallback (f32 staging, partials in d_out) ==
    float* part = (float*)d_out;
    gemm_k<64,64,true,1><<<dim3(D1/64, Nx/64), 256, 0, stream>>>(x0, nullptr, WtX1a, nullptr, Fx, 0, 1, 1, B1x, Nx, 0, 1.f);
    gemm_k<64,64,true,1><<<dim3(D1/64, Ny/64), 256, 0, stream>>>(y0, nullptr, WtX1b, nullptr, Fy, 0, 1, 1, B2x, Ny, 0, 1.f);
    gemm_k<64,64,true,1><<<dim3(D1/64, Ny/64), 256, 0, stream>>>(y0, nullptr, WtY1a, nullptr, Fy, 0, 1, 1, B1y, Ny, 0, 1.f);
    gemm_k<64,64,true,1><<<dim3(D1/64, Nx/64), 256, 0, stream>>>(x0, nullptr, WtY1b, nullptr, Fx, 0, 1, 1, B2y, Nx, 0, 1.f);

    gemm_k<128,128,true,0><<<dim3(D1/128, Nx/128, 4), 256, 0, stream>>>(hx1, hx2, (u16*)B1x, (u16*)B2x, Nx, Ny, 2, 4, part, D1, MNx1, 1.f);
    combine_k<<<dim3(2048), 256, 0, stream>>>(part, 4, D1, MNx1, bx1a, bx1b, alphap, x1, 1.f);
    gemm_k<128,128,true,0><<<dim3(D1/128, Ny/128, 8), 256, 0, stream>>>(hy1, hy2, (u16*)B1y, (u16*)B2y, Ny, Nx, 2, 8, part, D1, MNy1, 1.f);
    combine_k<<<dim3(1024), 256, 0, stream>>>(part, 8, D1, MNy1, by1a, by1b, betap, y1, 1.f);

    gemm_k<64,64,false,1><<<dim3(C/64, Nx/64), 256, 0, stream>>>(x1, nullptr, WtX2a, nullptr, D1, 0, 1, 1, B1x2, Nx, 0, 1.f);
    gemm_k<64,64,false,1><<<dim3(C/64, Ny/64), 256, 0, stream>>>(y1, nullptr, WtX2b, nullptr, D1, 0, 1, 1, B2x2, Ny, 0, 1.f);
    gemm_k<64,64,false,1><<<dim3(C/64, Ny/64), 256, 0, stream>>>(y1, nullptr, WtY2a, nullptr, D1, 0, 1, 1, B1y2, Ny, 0, 1.f);
    gemm_k<64,64,false,1><<<dim3(C/64, Nx/64), 256, 0, stream>>>(x1, nullptr, WtY2b, nullptr, D1, 0, 1, 1, B2y2, Nx, 0, 1.f);

    gemm_k<128,64,true,0><<<dim3(C/64, Nx/128, 8), 256, 0, stream>>>(hx1, hx2, (u16*)B1x2, (u16*)B2x2, Nx, Ny, 2, 8, part, C, MNx2, 1.f);
    combine_k<<<dim3(512), 256, 0, stream>>>(part, 8, C, MNx2, bx2a, bx2b, alphap, x2, 1.f);
    gemm_k<128,64,true,0><<<dim3(C/64, Ny/128, 16), 256, 0, stream>>>(hy1, hy2, (u16*)B1y2, (u16*)B2y2, Ny, Nx, 2, 16, part, C, MNy2, 1.f);
    combine_k<<<dim3(256), 256, 0, stream>>>(part, 16, C, MNy2, by2a, by2b, betap, y2, 1.f);
  }

  // h_hat = sigmoid(x2 @ y2^T) -> d_out (overwrites all scratch there)
  gemm_k<128,128,false,3><<<dim3(Ny/128, Nx/128, 1), 256, 0, stream>>>(x2, nullptr, y2, nullptr, C, 0, 1, 1, d_out, Ny, 0, 1.f);

  // x_output = log_softmax(x2)
  softmax_k<<<dim3(Nx/4), 256, 0, stream>>>(x2, (float*)d_out + (size_t)Nx * Ny);
}